// Round 2
// baseline (595.497 us; speedup 1.0000x reference)
//
#include <hip/hip_runtime.h>
#include <cstdint>
#include <cstddef>

// StripedHyena layer on MI355X.
// Pipeline: cast/prep -> unified MFMA GEMM (3 dilated convs + gate + res)
//   -> gated pointwise -> S4D chunked scan (Vandermonde GEMM, carry scan,
//      Toeplitz+cross GEMM) -> transpose-LayerNorm.
// Workspace use: ~399 MB.
// R2 fix: s1_states Vs staging covered only half the row (32 of 64 elems per
// half-stride) -> uninitialized LDS -> NaN. Now 8x f16x8 = 64 per thread.

#define B_ 8
#define L_ 4096
#define D_ 256
#define H_ 768
#define NST 32
#define LC 128
#define NC 32

typedef _Float16 f16;
typedef _Float16 f16x8 __attribute__((ext_vector_type(8)));
typedef float f32x4 __attribute__((ext_vector_type(4)));

__device__ __forceinline__ f32x4 mfma16(f16x8 a, f16x8 b, f32x4 c) {
  return __builtin_amdgcn_mfma_f32_16x16x32_f16(a, b, c, 0, 0, 0);
}

// ---------------- prep kernels ----------------

__global__ __launch_bounds__(256) void cast4(const float* __restrict__ s, f16* __restrict__ d) {
  int i = (blockIdx.x * 256 + threadIdx.x) * 4;
  float4 x = *(const float4*)(s + i);
  d[i + 0] = (f16)x.x; d[i + 1] = (f16)x.y; d[i + 2] = (f16)x.z; d[i + 3] = (f16)x.w;
}

// Build conv A-matrices: A[o][t*256 + j] = conv_w[o][j][t], fp16.
__global__ __launch_bounds__(256) void prep_convA(const float* __restrict__ w0,
                                                  const float* __restrict__ w1,
                                                  const float* __restrict__ w2,
                                                  f16* __restrict__ A) {
  int idx = blockIdx.x * 256 + threadIdx.x;  // grid covers exactly 1,638,400
  const int n0 = 256 * 256 * 3, n1 = 256 * 256 * 7;
  const float* w; int K, base;
  if (idx < n0) { w = w0; K = 3; base = 0; }
  else if (idx < n0 + n1) { idx -= n0; w = w1; K = 7; base = 256 * 768; }
  else { idx -= n0 + n1; w = w2; K = 15; base = 256 * 768 + 256 * 1792; }
  int o = idx / (256 * K); int r = idx - o * (256 * K); int j = r / K; int t = r - j * K;
  A[base + o * (256 * K) + t * 256 + j] = (f16)w[idx];
}

// Per (h,n): discretize SSM, emit A1 (Vandermonde for end-state GEMM),
// A2 (cross-term coefficients), WLc (chunk decay).
__global__ __launch_bounds__(256) void s4_params(const float* __restrict__ log_dt,
                                                 const float* __restrict__ A_re,
                                                 const float* __restrict__ A_im,
                                                 const float* __restrict__ C_re,
                                                 const float* __restrict__ C_im,
                                                 f16* __restrict__ A1, f16* __restrict__ A2,
                                                 float* __restrict__ WLc) {
  int idx = blockIdx.x * 256 + threadIdx.x;  // h*32+n, grid exact 24576
  int h = idx >> 5, n = idx & 31;
  float dt = expf(log_dt[h]);
  float Ar = A_re[idx], Ai = A_im[idx];
  float ar = dt * Ar, ai = dt * Ai;
  float e = expf(ar), sn, cs; sincosf(ai, &sn, &cs);
  float wr = e * cs, wi = e * sn;                 // w = exp(dt*A)
  float den = Ar * Ar + Ai * Ai;
  float Er = wr - 1.f, Ei = wi;
  float Cr = C_re[idx], Ci = C_im[idx];
  float nr = Cr * Er - Ci * Ei, ni = Cr * Ei + Ci * Er;
  float Cdr = (nr * Ar + ni * Ai) / den;          // C_disc = C*(w-1)/A
  float Cdi = (ni * Ar - nr * Ai) / den;
  // A1[ri][s] = Re/Im(w^(127-s)); incremental powers (drift ~1e-5)
  f16* A1r = A1 + ((size_t)h * 64 + 2 * n) * LC;
  f16* A1i = A1 + ((size_t)h * 64 + 2 * n + 1) * LC;
  float pr = 1.f, pi = 0.f;
  for (int j = 0; j < LC; ++j) {
    A1r[LC - 1 - j] = (f16)pr; A1i[LC - 1 - j] = (f16)pi;
    float t0 = pr * wr - pi * wi; pi = pr * wi + pi * wr; pr = t0;
  }
  WLc[idx * 2] = pr; WLc[idx * 2 + 1] = pi;       // w^128
  // A2[tau][2n] = 2*Re(Cd*w^(tau+1)), A2[tau][2n+1] = -2*Im(Cd*w^(tau+1))
  float qr = wr, qi = wi;
  for (int t = 0; t < LC; ++t) {
    A2[((size_t)h * LC + t) * 64 + 2 * n]     = (f16)(2.f * (Cdr * qr - Cdi * qi));
    A2[((size_t)h * LC + t) * 64 + 2 * n + 1] = (f16)(-2.f * (Cdr * qi + Cdi * qr));
    float t0 = qr * wr - qi * wi; qi = qr * wi + qi * wr; qr = t0;
  }
}

// kT[h][j] = 2*Re(sum_n Cd_n * w_n^j), j=0..127 (local Toeplitz kernel)
__global__ __launch_bounds__(256) void s4_kernelvec(const float* __restrict__ log_dt,
                                                    const float* __restrict__ A_re,
                                                    const float* __restrict__ A_im,
                                                    const float* __restrict__ C_re,
                                                    const float* __restrict__ C_im,
                                                    float* __restrict__ kT) {
  int idx = blockIdx.x * 256 + threadIdx.x;  // h*128+j, grid exact 98304
  int h = idx >> 7, j = idx & 127;
  float dt = expf(log_dt[h]);
  float acc = 0.f;
  for (int n = 0; n < NST; ++n) {
    float Ar = A_re[h * 32 + n], Ai = A_im[h * 32 + n];
    float ar = dt * Ar, ai = dt * Ai;
    float e1 = expf(ar), s1, c1; sincosf(ai, &s1, &c1);
    float wr = e1 * c1, wi = e1 * s1;
    float den = Ar * Ar + Ai * Ai;
    float Er = wr - 1.f, Ei = wi;
    float Cr = C_re[h * 32 + n], Ci = C_im[h * 32 + n];
    float nr = Cr * Er - Ci * Ei, ni = Cr * Ei + Ci * Er;
    float Cdr = (nr * Ar + ni * Ai) / den, Cdi = (ni * Ar - nr * Ai) / den;
    float ej = expf(ar * (float)j), sj, cj; sincosf(ai * (float)j, &sj, &cj);
    acc += 2.f * (Cdr * (ej * cj) - Cdi * (ej * sj));
  }
  kT[idx] = acc;
}

// ---------------- unified big GEMM: convs + gate + res ----------------
// grid (256 n-tiles, 18 m-tiles). mt 0-5: convs; 6-11: gate; 12-17: res.
// C[m][n] over B-matrix xh[(b,l)][j] with per-tap row offset (im2col-free).
__global__ __launch_bounds__(256) void gemm_all(
    const f16* __restrict__ xh, const f16* __restrict__ Aconv, const f16* __restrict__ Agr,
    const float* __restrict__ cb0, const float* __restrict__ cb1, const float* __restrict__ cb2,
    const float* __restrict__ gate_b, const float* __restrict__ res_b,
    f16* __restrict__ comb, f16* __restrict__ gate_s, f16* __restrict__ res) {
  __shared__ f16 As[128 * 72];
  __shared__ f16 Bs[128 * 72];
  const int mt = blockIdx.y, nt = blockIdx.x;
  const int b = nt >> 5, l0 = (nt & 31) * 128;
  const int tid = threadIdx.x;
  const f16* Abase; int Krow, taps, dil, m0, ci = 0;
  if (mt < 6) {
    ci = mt >> 1; m0 = (mt & 1) * 128;
    if (ci == 0)      { Abase = Aconv;                         Krow = 768;  taps = 3;  dil = 1; }
    else if (ci == 1) { Abase = Aconv + 256 * 768;             Krow = 1792; taps = 7;  dil = 2; }
    else              { Abase = Aconv + 256 * 768 + 256 * 1792; Krow = 3840; taps = 15; dil = 4; }
  } else if (mt < 12) { m0 = (mt - 6) * 128;  Abase = Agr;             Krow = 256; taps = 1; dil = 0; }
  else                { m0 = (mt - 12) * 128; Abase = Agr + 768 * 256; Krow = 256; taps = 1; dil = 0; }

  f32x4 acc[4][4];
#pragma unroll
  for (int i = 0; i < 4; ++i)
#pragma unroll
    for (int j = 0; j < 4; ++j) acc[i][j] = (f32x4){0.f, 0.f, 0.f, 0.f};

  const int wid = tid >> 6, lane = tid & 63, l15 = lane & 15, quad = lane >> 4;
  const int wm = (wid & 1) * 64, wn = (wid >> 1) * 64;
  const int srow = tid >> 1, shalf = tid & 1;

  for (int t = 0; t < taps; ++t) {
    int off = (t - (taps - 1) / 2) * dil;
    int gl = l0 + srow + off;
    bool inb = (gl >= 0) && (gl < L_);
    const f16* bsrc = xh + ((long)(b * L_ + gl)) * 256;
    const f16* asrc = Abase + (size_t)(m0 + srow) * Krow + t * 256;
    for (int kc = 0; kc < 4; ++kc) {   // 4 x BK=64
      {
        const f16x8* ap = (const f16x8*)(asrc + kc * 64 + shalf * 32);
        f16x8 a0 = ap[0], a1 = ap[1], a2 = ap[2], a3 = ap[3];
        f16x8* ad = (f16x8*)(&As[srow * 72 + shalf * 32]);
        ad[0] = a0; ad[1] = a1; ad[2] = a2; ad[3] = a3;
      }
      {
        f16x8 z = {0, 0, 0, 0, 0, 0, 0, 0};
        f16x8 b0 = z, b1 = z, b2 = z, b3 = z;
        if (inb) {
          const f16x8* bp = (const f16x8*)(bsrc + kc * 64 + shalf * 32);
          b0 = bp[0]; b1 = bp[1]; b2 = bp[2]; b3 = bp[3];
        }
        f16x8* bd = (f16x8*)(&Bs[srow * 72 + shalf * 32]);
        bd[0] = b0; bd[1] = b1; bd[2] = b2; bd[3] = b3;
      }
      __syncthreads();
#pragma unroll
      for (int k2 = 0; k2 < 2; ++k2) {
        f16x8 af[4], bf[4];
#pragma unroll
        for (int mi = 0; mi < 4; ++mi)
          af[mi] = *(const f16x8*)(&As[(wm + mi * 16 + l15) * 72 + k2 * 32 + quad * 8]);
#pragma unroll
        for (int ni = 0; ni < 4; ++ni)
          bf[ni] = *(const f16x8*)(&Bs[(wn + ni * 16 + l15) * 72 + k2 * 32 + quad * 8]);
#pragma unroll
        for (int mi = 0; mi < 4; ++mi)
#pragma unroll
          for (int ni = 0; ni < 4; ++ni) acc[mi][ni] = mfma16(af[mi], bf[ni], acc[mi][ni]);
      }
      __syncthreads();
    }
  }

  // epilogue
  if (mt < 6) {
    const float* cbias = (ci == 0) ? cb0 : (ci == 1 ? cb1 : cb2);
    int hbase = ci * 256 + m0;
#pragma unroll
    for (int mi = 0; mi < 4; ++mi)
#pragma unroll
      for (int ni = 0; ni < 4; ++ni) {
        int mg = wm + mi * 16 + quad * 4;
        int lg = l0 + wn + ni * 16 + l15;
#pragma unroll
        for (int r = 0; r < 4; ++r) {
          float val = acc[mi][ni][r] + cbias[m0 + mg + r];
          comb[((size_t)(b * H_ + hbase + mg + r)) * L_ + lg] = (f16)val;
        }
      }
  } else if (mt < 12) {
#pragma unroll
    for (int mi = 0; mi < 4; ++mi)
#pragma unroll
      for (int ni = 0; ni < 4; ++ni) {
        int lg = l0 + wn + ni * 16 + l15;
#pragma unroll
        for (int r = 0; r < 4; ++r) {
          int rr = m0 + wm + mi * 16 + quad * 4 + r;
          float val = acc[mi][ni][r] + gate_b[rr];
          float sg = 1.f / (1.f + expf(-val));
          gate_s[((size_t)(b * H_ + rr)) * L_ + lg] = (f16)sg;
        }
      }
  } else {
#pragma unroll
    for (int mi = 0; mi < 4; ++mi)
#pragma unroll
      for (int ni = 0; ni < 4; ++ni) {
        int lg = l0 + wn + ni * 16 + l15;
#pragma unroll
        for (int r = 0; r < 4; ++r) {
          int rr = m0 + wm + mi * 16 + quad * 4 + r;
          float val = acc[mi][ni][r] + res_b[rr];
          res[((size_t)(b * H_ + rr)) * L_ + lg] = (f16)val;
        }
      }
  }
}

// v = comb * gate_s (fp16, vectorized x8)
__global__ __launch_bounds__(256) void gate_mul(const f16* __restrict__ comb,
                                                const f16* __restrict__ gate,
                                                f16* __restrict__ v) {
  size_t i = ((size_t)blockIdx.x * 256 + threadIdx.x) * 8;
  f16x8 a = *(const f16x8*)(comb + i);
  f16x8 g = *(const f16x8*)(gate + i);
  *(f16x8*)(v + i) = a * g;
}

// ---------------- S4D: chunk end-states (per-h GEMM) ----------------
// Xend[b,h,c][ri] = sum_s A1[h][ri][s] * v[b,h,c*128+s].  grid (2, 768)
__global__ __launch_bounds__(256) void s1_states(const f16* __restrict__ v,
                                                 const f16* __restrict__ A1,
                                                 float* __restrict__ Xend) {
  __shared__ f16 A1s[64 * 136];
  __shared__ f16 Vs[128 * 136];
  const int h = blockIdx.y, cb = blockIdx.x;
  const int tid = threadIdx.x;
  {
    int row = tid >> 2, q = tid & 3;
    const f16x8* src = (const f16x8*)(A1 + ((size_t)h * 64 + row) * 128 + q * 32);
    f16x8* dst = (f16x8*)(&A1s[row * 136 + q * 32]);
    dst[0] = src[0]; dst[1] = src[1]; dst[2] = src[2]; dst[3] = src[3];
  }
  {
    int col = tid >> 1, half = tid & 1;
    int cg = cb * 128 + col, b = cg >> 5, c = cg & 31;
    const f16x8* src = (const f16x8*)(v + ((size_t)(b * H_ + h)) * L_ + c * 128 + half * 64);
    f16x8* dst = (f16x8*)(&Vs[col * 136 + half * 64]);
    dst[0] = src[0]; dst[1] = src[1]; dst[2] = src[2]; dst[3] = src[3];
    dst[4] = src[4]; dst[5] = src[5]; dst[6] = src[6]; dst[7] = src[7];
  }
  __syncthreads();
  const int wid = tid >> 6, lane = tid & 63, l15 = lane & 15, quad = lane >> 4;
  const int n0 = wid * 32;
  f32x4 acc[4][2];
#pragma unroll
  for (int i = 0; i < 4; ++i) { acc[i][0] = (f32x4){0,0,0,0}; acc[i][1] = (f32x4){0,0,0,0}; }
#pragma unroll
  for (int bk = 0; bk < 4; ++bk) {
    f16x8 af[4], bf[2];
#pragma unroll
    for (int mi = 0; mi < 4; ++mi)
      af[mi] = *(const f16x8*)(&A1s[(mi * 16 + l15) * 136 + bk * 32 + quad * 8]);
#pragma unroll
    for (int ni = 0; ni < 2; ++ni)
      bf[ni] = *(const f16x8*)(&Vs[(n0 + ni * 16 + l15) * 136 + bk * 32 + quad * 8]);
#pragma unroll
    for (int mi = 0; mi < 4; ++mi)
#pragma unroll
      for (int ni = 0; ni < 2; ++ni) acc[mi][ni] = mfma16(af[mi], bf[ni], acc[mi][ni]);
  }
#pragma unroll
  for (int mi = 0; mi < 4; ++mi)
#pragma unroll
    for (int ni = 0; ni < 2; ++ni) {
      int cg = cb * 128 + n0 + ni * 16 + l15, b = cg >> 5, c = cg & 31;
      float* dst = Xend + (((size_t)(b * H_ + h)) * NC + c) * 64 + mi * 16 + quad * 4;
      *(f32x4*)dst = acc[mi][ni];
    }
}

// sequential carry over 32 chunks; converts Xend -> Xin in place
__global__ __launch_bounds__(256) void s2_scan(float* __restrict__ X, const float* __restrict__ WLc) {
  int idx = blockIdx.x * 256 + threadIdx.x;  // (b*H+h)*32+n, grid exact 196608
  int n = idx & 31, bh = idx >> 5, h = bh % H_;
  float Wr = WLc[(h * NST + n) * 2], Wi = WLc[(h * NST + n) * 2 + 1];
  float xr = 0.f, xi = 0.f;
  float* base = X + (size_t)bh * NC * 64 + 2 * n;
  for (int c = 0; c < NC; ++c) {
    float er = base[c * 64], ei = base[c * 64 + 1];
    base[c * 64] = xr; base[c * 64 + 1] = xi;
    float t = Wr * xr - Wi * xi + er;
    xi = Wr * xi + Wi * xr + ei; xr = t;
  }
}

// y4 = Toeplitz(k_h) @ v_chunk + A2_h @ Xin + Dskip*v + res.  grid (4, 768)
__global__ __launch_bounds__(256) void s3_output(const f16* __restrict__ v,
                                                 const f16* __restrict__ A2g,
                                                 const f16* __restrict__ res,
                                                 const float* __restrict__ kT,
                                                 const float* __restrict__ Xin,
                                                 const float* __restrict__ Dskip,
                                                 float* __restrict__ y4) {
  __shared__ f16 Ts[128 * 136];   // phase2 aliases: A2s[128][72], Xs[64][72]
  __shared__ f16 Vs[64 * 136];
  __shared__ float kTs[128];
  f16* A2s = Ts;
  f16* Xs = Ts + 128 * 72;
  const int h = blockIdx.y, cb = blockIdx.x;
  const int tid = threadIdx.x;
  if (tid < 128) kTs[tid] = kT[h * 128 + tid];
  {
    int col = tid >> 2, q = tid & 3;
    int cg = cb * 64 + col, b = cg >> 5, c = cg & 31;
    const f16x8* src = (const f16x8*)(v + ((size_t)(b * H_ + h)) * L_ + c * 128 + q * 32);
    f16x8* dst = (f16x8*)(&Vs[col * 136 + q * 32]);
    dst[0] = src[0]; dst[1] = src[1]; dst[2] = src[2]; dst[3] = src[3];
  }
  __syncthreads();
  for (int i = 0; i < 64; ++i) {      // build Toeplitz tile
    int idx = tid * 64 + i, tau = idx >> 7, s = idx & 127;
    Ts[tau * 136 + s] = (f16)((s <= tau) ? kTs[tau - s] : 0.f);
  }
  __syncthreads();
  const int wid = tid >> 6, lane = tid & 63, l15 = lane & 15, quad = lane >> 4;
  const int wm = (wid & 1) * 64, wn = (wid >> 1) * 32;
  f32x4 acc[4][2];
#pragma unroll
  for (int i = 0; i < 4; ++i) { acc[i][0] = (f32x4){0,0,0,0}; acc[i][1] = (f32x4){0,0,0,0}; }
#pragma unroll
  for (int bk = 0; bk < 4; ++bk) {
    f16x8 af[4], bf[2];
#pragma unroll
    for (int mi = 0; mi < 4; ++mi)
      af[mi] = *(const f16x8*)(&Ts[(wm + mi * 16 + l15) * 136 + bk * 32 + quad * 8]);
#pragma unroll
    for (int ni = 0; ni < 2; ++ni)
      bf[ni] = *(const f16x8*)(&Vs[(wn + ni * 16 + l15) * 136 + bk * 32 + quad * 8]);
#pragma unroll
    for (int mi = 0; mi < 4; ++mi)
#pragma unroll
      for (int ni = 0; ni < 2; ++ni) acc[mi][ni] = mfma16(af[mi], bf[ni], acc[mi][ni]);
  }
  __syncthreads();  // done with Ts; restage as A2s + Xs
  {
    int row = tid >> 1, half = tid & 1;
    const f16x8* src = (const f16x8*)(A2g + ((size_t)h * 128 + row) * 64 + half * 32);
    f16x8* dst = (f16x8*)(&A2s[row * 72 + half * 32]);
    dst[0] = src[0]; dst[1] = src[1]; dst[2] = src[2]; dst[3] = src[3];
  }
  {
    int col = tid >> 2, part = tid & 3;
    int cg = cb * 64 + col, b = cg >> 5, c = cg & 31;
    const f32x4* src = (const f32x4*)(Xin + (((size_t)(b * H_ + h)) * NC + c) * 64 + part * 16);
    f16* dst = Xs + col * 72 + part * 16;
#pragma unroll
    for (int j = 0; j < 4; ++j) {
      f32x4 x = src[j];
      dst[j * 4 + 0] = (f16)x[0]; dst[j * 4 + 1] = (f16)x[1];
      dst[j * 4 + 2] = (f16)x[2]; dst[j * 4 + 3] = (f16)x[3];
    }
  }
  __syncthreads();
#pragma unroll
  for (int bk = 0; bk < 2; ++bk) {
    f16x8 af[4], bf[2];
#pragma unroll
    for (int mi = 0; mi < 4; ++mi)
      af[mi] = *(const f16x8*)(&A2s[(wm + mi * 16 + l15) * 72 + bk * 32 + quad * 8]);
#pragma unroll
    for (int ni = 0; ni < 2; ++ni)
      bf[ni] = *(const f16x8*)(&Xs[(wn + ni * 16 + l15) * 72 + bk * 32 + quad * 8]);
#pragma unroll
    for (int mi = 0; mi < 4; ++mi)
#pragma unroll
      for (int ni = 0; ni < 2; ++ni) acc[mi][ni] = mfma16(af[mi], bf[ni], acc[mi][ni]);
  }
  float Dh = Dskip[h];
#pragma unroll
  for (int mi = 0; mi < 4; ++mi)
#pragma unroll
    for (int ni = 0; ni < 2; ++ni) {
      int col = wn + ni * 16 + l15;
      int cg = cb * 64 + col, b = cg >> 5, c = cg & 31;
      int tau0 = wm + mi * 16 + quad * 4;
      size_t lbase = ((size_t)(b * H_ + h)) * L_ + c * 128 + tau0;
      const f16* rp = res + lbase;
      f32x4 o;
#pragma unroll
      for (int r = 0; r < 4; ++r)
        o[r] = acc[mi][ni][r] + Dh * (float)Vs[col * 136 + tau0 + r] + (float)rp[r];
      *(f32x4*)(y4 + lbase) = o;
    }
}

// transpose + LayerNorm over H=768.  grid (128 l-tiles, 8 b)
__global__ __launch_bounds__(256) void layernorm_t(const float* __restrict__ y4,
                                                   const float* __restrict__ gamma,
                                                   const float* __restrict__ beta,
                                                   float* __restrict__ out) {
  __shared__ f16 Ys[768 * 40];
  __shared__ float psum[256], psq[256], mu[32], rs[32];
  const int b = blockIdx.y, l0 = blockIdx.x * 32;
  const int tid = threadIdx.x;
#pragma unroll
  for (int p = 0; p < 3; ++p) {
    int hh = p * 256 + tid;
    const float* src = y4 + ((size_t)(b * H_ + hh)) * L_ + l0;
    f16* dst = Ys + hh * 40;
#pragma unroll
    for (int j = 0; j < 8; ++j) {
      float4 x = ((const float4*)src)[j];
      dst[j * 4 + 0] = (f16)x.x; dst[j * 4 + 1] = (f16)x.y;
      dst[j * 4 + 2] = (f16)x.z; dst[j * 4 + 3] = (f16)x.w;
    }
  }
  __syncthreads();
  {
    int l = tid & 31, hg = tid >> 5;
    float s = 0.f, s2 = 0.f;
    for (int k = 0; k < 96; ++k) {
      float val = (float)Ys[(hg * 96 + k) * 40 + l];
      s += val; s2 += val * val;
    }
    psum[hg * 32 + l] = s; psq[hg * 32 + l] = s2;
  }
  __syncthreads();
  if (tid < 32) {
    float S = 0.f, S2 = 0.f;
    for (int g = 0; g < 8; ++g) { S += psum[g * 32 + tid]; S2 += psq[g * 32 + tid]; }
    float m = S / 768.f;
    float var = S2 / 768.f - m * m;
    mu[tid] = m; rs[tid] = rsqrtf(var + 1e-5f);
  }
  __syncthreads();
  float g0 = gamma[tid], g1 = gamma[256 + tid], g2 = gamma[512 + tid];
  float be0 = beta[tid], be1 = beta[256 + tid], be2 = beta[512 + tid];
  for (int ll = 0; ll < 32; ++ll) {
    float m = mu[ll], r = rs[ll];
    size_t ob = ((size_t)b * L_ + l0 + ll) * H_;
    out[ob + tid]       = ((float)Ys[tid * 40 + ll] - m) * r * g0 + be0;
    out[ob + 256 + tid] = ((float)Ys[(256 + tid) * 40 + ll] - m) * r * g1 + be1;
    out[ob + 512 + tid] = ((float)Ys[(512 + tid) * 40 + ll] - m) * r * g2 + be2;
  }
}

// ---------------- launch ----------------
extern "C" void kernel_launch(void* const* d_in, const int* in_sizes, int n_in,
                              void* d_out, int out_size, void* d_ws, size_t ws_size,
                              hipStream_t stream) {
  const float* x      = (const float*)d_in[0];
  const float* cw0    = (const float*)d_in[1];
  const float* cb0    = (const float*)d_in[2];
  const float* cw1    = (const float*)d_in[3];
  const float* cb1    = (const float*)d_in[4];
  const float* cw2    = (const float*)d_in[5];
  const float* cb2    = (const float*)d_in[6];
  const float* gate_w = (const float*)d_in[7];
  const float* gate_b = (const float*)d_in[8];
  const float* res_w  = (const float*)d_in[9];
  const float* res_b  = (const float*)d_in[10];
  const float* log_dt = (const float*)d_in[11];
  const float* A_re   = (const float*)d_in[12];
  const float* A_im   = (const float*)d_in[13];
  const float* C_re   = (const float*)d_in[14];
  const float* C_im   = (const float*)d_in[15];
  const float* Dskip  = (const float*)d_in[16];
  const float* ln_g   = (const float*)d_in[17];
  const float* ln_b   = (const float*)d_in[18];
  float* out = (float*)d_out;

  char* ws = (char*)d_ws;
  f16*   xh   = (f16*)(ws + 0);            // 16,777,216
  f16*   Ac   = (f16*)(ws + 16777216);     //  3,276,800
  f16*   Ag   = (f16*)(ws + 20054016);     //    786,432
  f16*   comb = (f16*)(ws + 20840448);     // 50,331,648
  f16*   gts  = (f16*)(ws + 71172096);     // 50,331,648
  f16*   resb = (f16*)(ws + 121503744);    // 50,331,648
  f16*   vb   = (f16*)(ws + 171835392);    // 50,331,648
  f16*   A1   = (f16*)(ws + 222167040);    // 12,582,912
  f16*   A2   = (f16*)(ws + 234749952);    // 12,582,912
  float* kT   = (float*)(ws + 247332864);  //    393,216
  float* WLc  = (float*)(ws + 247726080);  //    196,608
  float* Xe   = (float*)(ws + 247922688);  // 50,331,648
  float* y4   = (float*)(ws + 298254336);  // 100,663,296  (total ~399 MB)

  cast4<<<8192, 256, 0, stream>>>(x, xh);                  // x -> fp16 B-matrix
  cast4<<<192, 256, 0, stream>>>(gate_w, Ag);
  cast4<<<192, 256, 0, stream>>>(res_w, Ag + 768 * 256);
  prep_convA<<<6400, 256, 0, stream>>>(cw0, cw1, cw2, Ac);
  s4_params<<<96, 256, 0, stream>>>(log_dt, A_re, A_im, C_re, C_im, A1, A2, WLc);
  s4_kernelvec<<<384, 256, 0, stream>>>(log_dt, A_re, A_im, C_re, C_im, kT);

  gemm_all<<<dim3(256, 18), 256, 0, stream>>>(xh, Ac, Ag, cb0, cb1, cb2, gate_b, res_b,
                                              comb, gts, resb);
  gate_mul<<<12288, 256, 0, stream>>>(comb, gts, vb);

  s1_states<<<dim3(2, 768), 256, 0, stream>>>(vb, A1, Xe);
  s2_scan<<<768, 256, 0, stream>>>(Xe, WLc);
  s3_output<<<dim3(4, 768), 256, 0, stream>>>(vb, A2, resb, kT, Xe, Dskip, y4);

  layernorm_t<<<dim3(128, 8), 256, 0, stream>>>(y4, ln_g, ln_b, out);
}